// Round 8
// baseline (104.883 us; speedup 1.0000x reference)
//
#include <hip/hip_runtime.h>
#include <math.h>

#define KN 500000
#define KGRID 128
#define KTGRID 64
#define KC 24
#define KL 16

// workspace layout:
// Tq: [4096 cells][16 labels] float4 (q, f32)          = 1 MB
// Tt: [4096 cells][16 labels] uint2 (t, bf16 pairs)    = 0.5 MB (read as uint4 chunks)
// Tl: [3*16384 cells][4] float4 (label feats, f32)     = 3 MB
#define TQ_BYTES (KTGRID * KTGRID * KL * 16)
#define TT_BYTES (KTGRID * KTGRID * KL * 8)
#define TL_BYTES (3 * KGRID * KGRID * KL * 4)
#define WS_NEEDED ((size_t)(TQ_BYTES + TT_BYTES + TL_BYTES))

#define BLK 128   // 2 waves per block

typedef float vf4 __attribute__((ext_vector_type(4)));

__device__ __forceinline__ float4 nt_load4(const void* p) {
    vf4 v = __builtin_nontemporal_load((const vf4*)p);
    return make_float4(v.x, v.y, v.z, v.w);
}
__device__ __forceinline__ void nt_store4(void* p, float4 f) {
    vf4 v = {f.x, f.y, f.z, f.w};
    __builtin_nontemporal_store(v, (vf4*)p);
}
__device__ __forceinline__ float nt_loadf(const float* p) { return __builtin_nontemporal_load(p); }
__device__ __forceinline__ void nt_storef(float* p, float v) { __builtin_nontemporal_store(v, p); }

__device__ __forceinline__ uint32_t f2bf(float f) {
    uint32_t u = __float_as_uint(f);
    return (u + 0x7fffu + ((u >> 16) & 1u)) >> 16;   // RNE
}
__device__ __forceinline__ uint32_t pack2(float a, float b) {
    return f2bf(a) | (f2bf(b) << 16);
}
__device__ __forceinline__ float bf_lo(uint32_t u) { return __uint_as_float(u << 16); }
__device__ __forceinline__ float bf_hi(uint32_t u) { return __uint_as_float(u & 0xffff0000u); }

// ---- fused precompute: blocks [0,256) -> deform transform, [256,448) -> label transform ----
__global__ __launch_bounds__(256) void xform_all(
    const float* __restrict__ dp, const float* __restrict__ Wd,
    const float* __restrict__ lp, const float* __restrict__ Wl,
    float4* __restrict__ Tq, uint2* __restrict__ Tt, float4* __restrict__ Tl)
{
    if (blockIdx.x < 256) {
        __shared__ float sW[112 * KC];
        for (int i = threadIdx.x; i < 112 * KC; i += 256) sW[i] = Wd[i];
        __syncthreads();
        int t = blockIdx.x * 256 + threadIdx.x;   // < 65536 exactly
        int cell = t >> 4, l = t & 15;
        float f[KC];
        #pragma unroll
        for (int c = 0; c < KC; ++c) f[c] = dp[c * (KTGRID * KTGRID) + cell];
        float o[7];
        #pragma unroll
        for (int jj = 0; jj < 7; ++jj) {
            const float* wr = sW + (l * 7 + jj) * KC;
            float acc = 0.0f;
            #pragma unroll
            for (int c = 0; c < KC; ++c) acc = fmaf(f[c], wr[c], acc);
            o[jj] = acc;
        }
        Tq[cell * 16 + l] = make_float4(o[0], o[1], o[2], o[3]);
        Tt[cell * 16 + l] = make_uint2(pack2(o[4], o[5]), pack2(o[6], 0.0f));
    } else {
        __shared__ float sW2[KL * 72];
        for (int i = threadIdx.x; i < KL * 72; i += 256) sW2[i] = Wl[i];
        __syncthreads();
        int t = (blockIdx.x - 256) * 256 + threadIdx.x;   // < 49152 exactly
        int p = t / (KGRID * KGRID);
        int cell = t - p * (KGRID * KGRID);
        float f[KC];
        #pragma unroll
        for (int c = 0; c < KC; ++c) f[c] = lp[(size_t)(p * KC + c) * (KGRID * KGRID) + cell];
        #pragma unroll
        for (int k4 = 0; k4 < 4; ++k4) {
            float o[4];
            #pragma unroll
            for (int kk = 0; kk < 4; ++kk) {
                const float* wr = sW2 + (k4 * 4 + kk) * 72 + p * KC;
                float acc = 0.0f;
                #pragma unroll
                for (int c = 0; c < KC; ++c) acc = fmaf(f[c], wr[c], acc);
                o[kk] = acc;
            }
            Tl[t * 4 + k4] = make_float4(o[0], o[1], o[2], o[3]);
        }
    }
}

// ---- main: phased, 4-lane cooperative gathers, low-VGPR for occupancy ----
// sBil per point, stride 11 (gcd(11,32)=1 -> conflict-free):
//   in: [0..2]=pn, [3]=ts, [4]=tt; phase C writes [4..7]=q, [8..10]=t
// sLf per point, stride 20 (16B-aligned): lf[16] -> lab[16] in place
__global__ __launch_bounds__(BLK, 8) void hexplane_main(
    const float* __restrict__ pts, const float* __restrict__ rots,
    const float* __restrict__ tsrc, const float* __restrict__ ttgt,
    const float4* __restrict__ Tq, const uint4* __restrict__ Tt,
    const float4* __restrict__ Tl, float* __restrict__ out)
{
    __shared__ uint32_t sBil[BLK * 11];
    __shared__ float sLf[BLK * 20];

    const int tid = threadIdx.x;
    const int base = blockIdx.x * BLK;
    const int gid = base + tid;
    const bool valid = gid < KN;

    // ---- Phase A0: per-thread input load (nontemporal), publish coords ----
    if (valid) {
        float px = nt_loadf(&pts[gid * 3 + 0]);
        float py = nt_loadf(&pts[gid * 3 + 1]);
        float pz = nt_loadf(&pts[gid * 3 + 2]);
        float ts = nt_loadf(&tsrc[gid]);
        float tt = nt_loadf(&ttgt[gid]);
        sBil[tid * 11 + 0] = __float_as_uint(-px);
        sBil[tid * 11 + 1] = __float_as_uint(-py);
        sBil[tid * 11 + 2] = __float_as_uint(-pz);
        sBil[tid * 11 + 3] = __float_as_uint(ts);
        sBil[tid * 11 + 4] = __float_as_uint(tt);
    }
    __syncthreads();

    const int g = tid >> 2, j = tid & 3;   // 32 groups of 4 lanes

    // ---- Phase A: cooperative Tl gather -> lf[16] in LDS (lane j owns labels 4j..4j+3) ----
    #pragma unroll
    for (int r = 0; r < 4; ++r) {
        int p = r * (BLK / 4) + g;
        if (base + p < KN) {
            float pn0 = __uint_as_float(sBil[p * 11 + 0]);
            float pn1 = __uint_as_float(sBil[p * 11 + 1]);
            float pn2 = __uint_as_float(sBil[p * 11 + 2]);
            float a0 = 0.f, a1 = 0.f, a2 = 0.f, a3 = 0.f;
            #pragma unroll
            for (int pl = 0; pl < 3; ++pl) {
                float cx = (pl == 0) ? pn0 : (pl == 1) ? pn0 : pn1;
                float cy = (pl == 0) ? pn1 : (pl == 1) ? pn2 : pn2;
                float x = (cx + 1.0f) * 63.5f;
                float y = (cy + 1.0f) * 63.5f;
                float xf = floorf(x), yf = floorf(y);
                float wx = x - xf, wy = y - yf;
                int x0 = min((int)xf, KGRID - 1);
                int x1 = min(x0 + 1, KGRID - 1);
                int y0 = min((int)yf, KGRID - 1);
                int y1 = min(y0 + 1, KGRID - 1);
                const float4* B = Tl + (size_t)pl * (KGRID * KGRID * 4);
                float4 A = B[(y0 * KGRID + x0) * 4 + j];
                float4 Bc = B[(y0 * KGRID + x1) * 4 + j];
                float4 Cc = B[(y1 * KGRID + x0) * 4 + j];
                float4 D = B[(y1 * KGRID + x1) * 4 + j];
                float w00 = (1.f - wx) * (1.f - wy), w01 = wx * (1.f - wy);
                float w10 = (1.f - wx) * wy,          w11 = wx * wy;
                a0 = fmaf(w00, A.x, fmaf(w01, Bc.x, fmaf(w10, Cc.x, fmaf(w11, D.x, a0))));
                a1 = fmaf(w00, A.y, fmaf(w01, Bc.y, fmaf(w10, Cc.y, fmaf(w11, D.y, a1))));
                a2 = fmaf(w00, A.z, fmaf(w01, Bc.z, fmaf(w10, Cc.z, fmaf(w11, D.z, a2))));
                a3 = fmaf(w00, A.w, fmaf(w01, Bc.w, fmaf(w10, Cc.w, fmaf(w11, D.w, a3))));
            }
            *reinterpret_cast<float4*>(&sLf[p * 20 + j * 4]) = make_float4(a0, a1, a2, a3);
        }
    }
    __syncthreads();

    // ---- Phase B: per-thread softmax -> lab; store label output NOW (frees regs) ----
    if (valid) {
        float lf[16];
        #pragma unroll
        for (int m4 = 0; m4 < 4; ++m4) {
            float4 v = *reinterpret_cast<float4*>(&sLf[tid * 20 + m4 * 4]);
            lf[m4 * 4 + 0] = v.x; lf[m4 * 4 + 1] = v.y;
            lf[m4 * 4 + 2] = v.z; lf[m4 * 4 + 3] = v.w;
        }
        float mx = lf[0];
        #pragma unroll
        for (int k = 1; k < 16; ++k) mx = fmaxf(mx, lf[k]);
        float s = 0.f;
        float lab[16];
        #pragma unroll
        for (int k = 0; k < 16; ++k) {
            float e = __expf((lf[k] - mx) * 10.0f);
            lab[k] = e; s += e;
        }
        float rs = 1.0f / s;
        #pragma unroll
        for (int k = 0; k < 16; ++k) lab[k] *= rs;
        float4* lab_out = reinterpret_cast<float4*>(out + (size_t)KN * 7);
        #pragma unroll
        for (int m4 = 0; m4 < 4; ++m4) {
            float4 lv = make_float4(lab[m4 * 4 + 0], lab[m4 * 4 + 1],
                                    lab[m4 * 4 + 2], lab[m4 * 4 + 3]);
            *reinterpret_cast<float4*>(&sLf[tid * 20 + m4 * 4]) = lv;
            nt_store4(&lab_out[(size_t)gid * 4 + m4], lv);
        }
    }
    __syncthreads();

    // ---- Phase C: cooperative Tq/Tt gather + normalize + weighted sum -> qt in LDS ----
    #pragma unroll
    for (int r = 0; r < 4; ++r) {
        int p = r * (BLK / 4) + g;
        if (base + p < KN) {
            float ts = __uint_as_float(sBil[p * 11 + 3]);
            float tt = __uint_as_float(sBil[p * 11 + 4]);
            float x = (ts + 1.0f) * 31.5f, y = (tt + 1.0f) * 31.5f;
            float xf = floorf(x), yf = floorf(y);
            float wx = x - xf, wy = y - yf;
            int x0 = min((int)xf, KTGRID - 1);
            int x1 = min(x0 + 1, KTGRID - 1);
            int y0 = min((int)yf, KTGRID - 1);
            int y1 = min(y0 + 1, KTGRID - 1);
            int c00 = y0 * KTGRID + x0, c01 = y0 * KTGRID + x1;
            int c10 = y1 * KTGRID + x0, c11 = y1 * KTGRID + x1;
            float w00 = (1.f - wx) * (1.f - wy), w01 = wx * (1.f - wy);
            float w10 = (1.f - wx) * wy,          w11 = wx * wy;

            // q part: lane j owns labels {j, 4+j, 8+j, 12+j} (f32)
            float q0 = 0.f, q1 = 0.f, q2 = 0.f, q3 = 0.f;
            #pragma unroll
            for (int m = 0; m < 4; ++m) {
                int l = m * 4 + j;
                float4 qa = Tq[c00 * 16 + l], qb = Tq[c01 * 16 + l];
                float4 qc4 = Tq[c10 * 16 + l], qd = Tq[c11 * 16 + l];
                float lw = sLf[p * 20 + l];
                float v0 = fmaf(w00, qa.x, fmaf(w01, qb.x, fmaf(w10, qc4.x, w11 * qd.x)));
                float v1 = fmaf(w00, qa.y, fmaf(w01, qb.y, fmaf(w10, qc4.y, w11 * qd.y)));
                float v2 = fmaf(w00, qa.z, fmaf(w01, qb.z, fmaf(w10, qc4.z, w11 * qd.z)));
                float v3 = fmaf(w00, qa.w, fmaf(w01, qb.w, fmaf(w10, qc4.w, w11 * qd.w)));
                float nrm = sqrtf(v0*v0 + v1*v1 + v2*v2 + v3*v3);
                float wi = lw / fmaxf(nrm, 1e-12f);
                q0 = fmaf(v0, wi, q0); q1 = fmaf(v1, wi, q1);
                q2 = fmaf(v2, wi, q2); q3 = fmaf(v3, wi, q3);
            }

            // t part: chunk n*4+j covers labels {8n+2j, 8n+2j+1} (bf16)
            float t0 = 0.f, t1 = 0.f, t2 = 0.f;
            #pragma unroll
            for (int n = 0; n < 2; ++n) {
                int ch = n * 4 + j;
                uint4 ua = Tt[c00 * 8 + ch], ub = Tt[c01 * 8 + ch];
                uint4 uc = Tt[c10 * 8 + ch], ud = Tt[c11 * 8 + ch];
                int lA = n * 8 + j * 2;
                float lwA = sLf[p * 20 + lA], lwB = sLf[p * 20 + lA + 1];
                float a0 = fmaf(w00, bf_lo(ua.x), fmaf(w01, bf_lo(ub.x), fmaf(w10, bf_lo(uc.x), w11 * bf_lo(ud.x))));
                float a1 = fmaf(w00, bf_hi(ua.x), fmaf(w01, bf_hi(ub.x), fmaf(w10, bf_hi(uc.x), w11 * bf_hi(ud.x))));
                float a2 = fmaf(w00, bf_lo(ua.y), fmaf(w01, bf_lo(ub.y), fmaf(w10, bf_lo(uc.y), w11 * bf_lo(ud.y))));
                float b0 = fmaf(w00, bf_lo(ua.z), fmaf(w01, bf_lo(ub.z), fmaf(w10, bf_lo(uc.z), w11 * bf_lo(ud.z))));
                float b1 = fmaf(w00, bf_hi(ua.z), fmaf(w01, bf_hi(ub.z), fmaf(w10, bf_hi(uc.z), w11 * bf_hi(ud.z))));
                float b2 = fmaf(w00, bf_lo(ua.w), fmaf(w01, bf_lo(ub.w), fmaf(w10, bf_lo(uc.w), w11 * bf_lo(ud.w))));
                t0 = fmaf(lwA, a0, fmaf(lwB, b0, t0));
                t1 = fmaf(lwA, a1, fmaf(lwB, b1, t1));
                t2 = fmaf(lwA, a2, fmaf(lwB, b2, t2));
            }

            q0 += __shfl_xor(q0, 1); q0 += __shfl_xor(q0, 2);
            q1 += __shfl_xor(q1, 1); q1 += __shfl_xor(q1, 2);
            q2 += __shfl_xor(q2, 1); q2 += __shfl_xor(q2, 2);
            q3 += __shfl_xor(q3, 1); q3 += __shfl_xor(q3, 2);
            t0 += __shfl_xor(t0, 1); t0 += __shfl_xor(t0, 2);
            t1 += __shfl_xor(t1, 1); t1 += __shfl_xor(t1, 2);
            t2 += __shfl_xor(t2, 1); t2 += __shfl_xor(t2, 2);
            if (j == 0) {
                sBil[p * 11 + 4] = __float_as_uint(q0);
                sBil[p * 11 + 5] = __float_as_uint(q1);
                sBil[p * 11 + 6] = __float_as_uint(q2);
                sBil[p * 11 + 7] = __float_as_uint(q3);
                sBil[p * 11 + 8] = __float_as_uint(t0);
                sBil[p * 11 + 9] = __float_as_uint(t1);
                sBil[p * 11 + 10] = __float_as_uint(t2);
            }
        }
    }
    __syncthreads();

    // ---- Phase D: per-thread epilogue (reload rq here; p recovered from LDS) ----
    if (valid) {
        float px = -__uint_as_float(sBil[tid * 11 + 0]);
        float py = -__uint_as_float(sBil[tid * 11 + 1]);
        float pz = -__uint_as_float(sBil[tid * 11 + 2]);
        float qw = __uint_as_float(sBil[tid * 11 + 4]);
        float qx = __uint_as_float(sBil[tid * 11 + 5]);
        float qy = __uint_as_float(sBil[tid * 11 + 6]);
        float qz = __uint_as_float(sBil[tid * 11 + 7]);
        float trx = __uint_as_float(sBil[tid * 11 + 8]);
        float tryy = __uint_as_float(sBil[tid * 11 + 9]);
        float trz = __uint_as_float(sBil[tid * 11 + 10]);
        float4 rq = nt_load4(&reinterpret_cast<const float4*>(rots)[gid]);

        float tw = -(qx * px + qy * py + qz * pz);
        float tx = qw * px + qy * pz - qz * py;
        float ty = qw * py - qx * pz + qz * px;
        float tz = qw * pz + qx * py - qy * px;
        float ox = -tw * qx + tx * qw - ty * qz + tz * qy;
        float oy = -tw * qy + tx * qz + ty * qw - tz * qx;
        float oz = -tw * qz - tx * qy + ty * qx + tz * qw;

        nt_storef(&out[gid * 3 + 0], ox + trx);
        nt_storef(&out[gid * 3 + 1], oy + tryy);
        nt_storef(&out[gid * 3 + 2], oz + trz);

        float rw = rq.x, rx = rq.y, ry = rq.z, rz = rq.w;
        float mw = qw * rw - qx * rx - qy * ry - qz * rz;
        float mx2 = qw * rx + qx * rw + qy * rz - qz * ry;
        float my = qw * ry - qx * rz + qy * rw + qz * rx;
        float mz = qw * rz + qx * ry - qy * rx + qz * rw;
        if (mw < 0.0f) { mw = -mw; mx2 = -mx2; my = -my; mz = -mz; }
        nt_store4(&reinterpret_cast<float4*>(out + (size_t)KN * 3)[gid],
                  make_float4(mw, mx2, my, mz));
    }
}

// ======== fallback (round-1 kernel, used only if ws_size too small) ========
struct Bilin { int i00, i01, i10, i11; float w00, w01, w10, w11; };

__device__ __forceinline__ Bilin make_bilin(float cx, float cy, int W, int H) {
    float x = (cx + 1.0f) * 0.5f * (float)(W - 1);
    float y = (cy + 1.0f) * 0.5f * (float)(H - 1);
    float x0f = floorf(x), y0f = floorf(y);
    float wx = x - x0f, wy = y - y0f;
    int x0 = max(0, min((int)x0f, W - 1));
    int x1 = min(x0 + 1, W - 1);
    int y0 = max(0, min((int)y0f, H - 1));
    int y1 = min(y0 + 1, H - 1);
    Bilin b;
    b.i00 = y0 * W + x0; b.i01 = y0 * W + x1;
    b.i10 = y1 * W + x0; b.i11 = y1 * W + x1;
    b.w00 = (1.0f - wx) * (1.0f - wy); b.w01 = wx * (1.0f - wy);
    b.w10 = (1.0f - wx) * wy;          b.w11 = wx * wy;
    return b;
}

__global__ __launch_bounds__(256) void hexplane_fallback(
    const float* __restrict__ pts, const float* __restrict__ rots,
    const float* __restrict__ tsrc, const float* __restrict__ ttgt,
    const float* __restrict__ label_planes, const float* __restrict__ deform_plane,
    const float* __restrict__ W_label, const float* __restrict__ W_deform,
    float* __restrict__ out)
{
    __shared__ float sWd[112 * KC];
    __shared__ float sWl[KL * 72];
    for (int i = threadIdx.x; i < 112 * KC; i += blockDim.x) sWd[i] = W_deform[i];
    for (int i = threadIdx.x; i < KL * 72; i += blockDim.x) sWl[i] = W_label[i];
    __syncthreads();
    int idx = blockIdx.x * blockDim.x + threadIdx.x;
    if (idx >= KN) return;
    float px = pts[idx*3], py = pts[idx*3+1], pz = pts[idx*3+2];
    float4 rq = reinterpret_cast<const float4*>(rots)[idx];
    Bilin bd = make_bilin(tsrc[idx], ttgt[idx], KTGRID, KTGRID);
    float tfeat[KC];
    #pragma unroll
    for (int c = 0; c < KC; ++c) {
        const float* pl = deform_plane + c * (KTGRID * KTGRID);
        tfeat[c] = fmaf(bd.w11, pl[bd.i11], fmaf(bd.w10, pl[bd.i10], fmaf(bd.w01, pl[bd.i01], bd.w00 * pl[bd.i00])));
    }
    float pn0 = -px, pn1 = -py, pn2 = -pz;
    float lf[KL];
    #pragma unroll
    for (int k = 0; k < KL; ++k) lf[k] = 0.0f;
    #pragma unroll
    for (int p = 0; p < 3; ++p) {
        float cx = (p == 0) ? pn0 : (p == 1) ? pn0 : pn1;
        float cy = (p == 0) ? pn1 : (p == 1) ? pn2 : pn2;
        Bilin bl = make_bilin(cx, cy, KGRID, KGRID);
        const float* plane_p = label_planes + p * (KC * KGRID * KGRID);
        #pragma unroll
        for (int c = 0; c < KC; ++c) {
            const float* pl = plane_p + c * (KGRID * KGRID);
            float v = fmaf(bl.w11, pl[bl.i11], fmaf(bl.w10, pl[bl.i10], fmaf(bl.w01, pl[bl.i01], bl.w00 * pl[bl.i00])));
            #pragma unroll
            for (int k = 0; k < KL; ++k) lf[k] = fmaf(v, sWl[k * 72 + p * KC + c], lf[k]);
        }
    }
    float m = lf[0];
    #pragma unroll
    for (int k = 1; k < KL; ++k) m = fmaxf(m, lf[k]);
    float lab[KL], ssum = 0.0f;
    #pragma unroll
    for (int k = 0; k < KL; ++k) { float e = __expf((lf[k] - m) * 10.0f); lab[k] = e; ssum += e; }
    float rs = 1.0f / ssum;
    #pragma unroll
    for (int k = 0; k < KL; ++k) lab[k] *= rs;
    float qw = 0, qx = 0, qy = 0, qz = 0, trx = 0, tryy = 0, trz = 0;
    #pragma unroll
    for (int l = 0; l < KL; ++l) {
        float d[7];
        #pragma unroll
        for (int jj = 0; jj < 7; ++jj) {
            const float* wr = sWd + (l * 7 + jj) * KC;
            float acc = 0.0f;
            #pragma unroll
            for (int c = 0; c < KC; ++c) acc = fmaf(tfeat[c], wr[c], acc);
            d[jj] = acc;
        }
        float inv = 1.0f / fmaxf(sqrtf(d[0]*d[0]+d[1]*d[1]+d[2]*d[2]+d[3]*d[3]), 1e-12f);
        float w = lab[l], wi = w * inv;
        qw = fmaf(d[0], wi, qw); qx = fmaf(d[1], wi, qx); qy = fmaf(d[2], wi, qy); qz = fmaf(d[3], wi, qz);
        trx = fmaf(d[4], w, trx); tryy = fmaf(d[5], w, tryy); trz = fmaf(d[6], w, trz);
    }
    float tw = -(qx*px + qy*py + qz*pz);
    float tx = qw*px + qy*pz - qz*py;
    float ty = qw*py - qx*pz + qz*px;
    float tz = qw*pz + qx*py - qy*px;
    out[idx*3+0] = -tw*qx + tx*qw - ty*qz + tz*qy + trx;
    out[idx*3+1] = -tw*qy + tx*qz + ty*qw - tz*qx + tryy;
    out[idx*3+2] = -tw*qz - tx*qy + ty*qx + tz*qw + trz;
    float rw = rq.x, rx = rq.y, ry = rq.z, rz = rq.w;
    float mw = qw*rw - qx*rx - qy*ry - qz*rz;
    float mx = qw*rx + qx*rw + qy*rz - qz*ry;
    float my = qw*ry - qx*rz + qy*rw + qz*rx;
    float mz = qw*rz + qx*ry - qy*rx + qz*rw;
    if (mw < 0.0f) { mw = -mw; mx = -mx; my = -my; mz = -mz; }
    reinterpret_cast<float4*>(out + (size_t)KN * 3)[idx] = make_float4(mw, mx, my, mz);
    float4* lab_out = reinterpret_cast<float4*>(out + (size_t)KN * 7);
    #pragma unroll
    for (int k = 0; k < 4; ++k)
        lab_out[idx*4+k] = make_float4(lab[k*4], lab[k*4+1], lab[k*4+2], lab[k*4+3]);
}

extern "C" void kernel_launch(void* const* d_in, const int* in_sizes, int n_in,
                              void* d_out, int out_size, void* d_ws, size_t ws_size,
                              hipStream_t stream) {
    const float* pts  = (const float*)d_in[0];
    const float* rots = (const float*)d_in[1];
    const float* ts   = (const float*)d_in[2];
    const float* tt   = (const float*)d_in[3];
    const float* lp   = (const float*)d_in[4];
    const float* dp   = (const float*)d_in[5];
    const float* wl   = (const float*)d_in[6];
    const float* wd   = (const float*)d_in[7];
    float* out = (float*)d_out;

    if (ws_size < WS_NEEDED) {
        hexplane_fallback<<<dim3((KN + 255) / 256), dim3(256), 0, stream>>>(
            pts, rots, ts, tt, lp, dp, wl, wd, out);
        return;
    }

    unsigned char* ws = (unsigned char*)d_ws;
    float4* Tq = (float4*)ws;
    uint2*  Tt = (uint2*)(ws + TQ_BYTES);
    float4* Tl = (float4*)(ws + TQ_BYTES + TT_BYTES);

    xform_all<<<dim3(448), dim3(256), 0, stream>>>(dp, wd, lp, wl, Tq, Tt, Tl);
    hexplane_main<<<dim3((KN + BLK - 1) / BLK), dim3(BLK), 0, stream>>>(
        pts, rots, ts, tt, Tq, (const uint4*)Tt, Tl, out);
}

// Round 9
// 91.556 us; speedup vs baseline: 1.1456x; 1.1456x over previous
//
#include <hip/hip_runtime.h>
#include <math.h>

#define KN 500000
#define KGRID 128
#define KTGRID 64
#define KC 24
#define KL 16

// workspace layout:
// Tq: [4096 cells][16 labels] float4 (q, f32)          = 1 MB
// Tt: [4096 cells][16 labels] uint2 (t, bf16 pairs)    = 0.5 MB (read as uint4 chunks)
// Tl: [3*16384 cells][4] float4 (label feats, f32)     = 3 MB
#define TQ_BYTES (KTGRID * KTGRID * KL * 16)
#define TT_BYTES (KTGRID * KTGRID * KL * 8)
#define TL_BYTES (3 * KGRID * KGRID * KL * 4)
#define WS_NEEDED ((size_t)(TQ_BYTES + TT_BYTES + TL_BYTES))

typedef float vf4 __attribute__((ext_vector_type(4)));

__device__ __forceinline__ float4 nt_load4(const void* p) {
    vf4 v = __builtin_nontemporal_load((const vf4*)p);
    return make_float4(v.x, v.y, v.z, v.w);
}
__device__ __forceinline__ void nt_store4(void* p, float4 f) {
    vf4 v = {f.x, f.y, f.z, f.w};
    __builtin_nontemporal_store(v, (vf4*)p);
}
__device__ __forceinline__ float nt_loadf(const float* p) { return __builtin_nontemporal_load(p); }
__device__ __forceinline__ void nt_storef(float* p, float v) { __builtin_nontemporal_store(v, p); }

__device__ __forceinline__ uint32_t f2bf(float f) {
    uint32_t u = __float_as_uint(f);
    return (u + 0x7fffu + ((u >> 16) & 1u)) >> 16;   // RNE
}
__device__ __forceinline__ uint32_t pack2(float a, float b) {
    return f2bf(a) | (f2bf(b) << 16);
}
__device__ __forceinline__ float bf_lo(uint32_t u) { return __uint_as_float(u << 16); }
__device__ __forceinline__ float bf_hi(uint32_t u) { return __uint_as_float(u & 0xffff0000u); }

// ---- fused precompute: blocks [0,256) -> deform transform, [256,448) -> label transform ----
__global__ __launch_bounds__(256) void xform_all(
    const float* __restrict__ dp, const float* __restrict__ Wd,
    const float* __restrict__ lp, const float* __restrict__ Wl,
    float4* __restrict__ Tq, uint2* __restrict__ Tt, float4* __restrict__ Tl)
{
    if (blockIdx.x < 256) {
        __shared__ float sW[112 * KC];
        for (int i = threadIdx.x; i < 112 * KC; i += 256) sW[i] = Wd[i];
        __syncthreads();
        int t = blockIdx.x * 256 + threadIdx.x;   // < 65536 exactly
        int cell = t >> 4, l = t & 15;
        float f[KC];
        #pragma unroll
        for (int c = 0; c < KC; ++c) f[c] = dp[c * (KTGRID * KTGRID) + cell];
        float o[7];
        #pragma unroll
        for (int jj = 0; jj < 7; ++jj) {
            const float* wr = sW + (l * 7 + jj) * KC;
            float acc = 0.0f;
            #pragma unroll
            for (int c = 0; c < KC; ++c) acc = fmaf(f[c], wr[c], acc);
            o[jj] = acc;
        }
        Tq[cell * 16 + l] = make_float4(o[0], o[1], o[2], o[3]);
        Tt[cell * 16 + l] = make_uint2(pack2(o[4], o[5]), pack2(o[6], 0.0f));
    } else {
        __shared__ float sW2[KL * 72];
        for (int i = threadIdx.x; i < KL * 72; i += 256) sW2[i] = Wl[i];
        __syncthreads();
        int t = (blockIdx.x - 256) * 256 + threadIdx.x;   // < 49152 exactly
        int p = t / (KGRID * KGRID);
        int cell = t - p * (KGRID * KGRID);
        float f[KC];
        #pragma unroll
        for (int c = 0; c < KC; ++c) f[c] = lp[(size_t)(p * KC + c) * (KGRID * KGRID) + cell];
        #pragma unroll
        for (int k4 = 0; k4 < 4; ++k4) {
            float o[4];
            #pragma unroll
            for (int kk = 0; kk < 4; ++kk) {
                const float* wr = sW2 + (k4 * 4 + kk) * 72 + p * KC;
                float acc = 0.0f;
                #pragma unroll
                for (int c = 0; c < KC; ++c) acc = fmaf(f[c], wr[c], acc);
                o[kk] = acc;
            }
            Tl[t * 4 + k4] = make_float4(o[0], o[1], o[2], o[3]);
        }
    }
}

// ---- main: single-wave blocks, phased, 4-lane cooperative gathers, full-line stores ----
__global__ __launch_bounds__(64) void hexplane_main(
    const float* __restrict__ pts, const float* __restrict__ rots,
    const float* __restrict__ tsrc, const float* __restrict__ ttgt,
    const float4* __restrict__ Tq, const uint4* __restrict__ Tt,
    const float4* __restrict__ Tl, float* __restrict__ out)
{
    // sBil per point, stride 9 (gcd(9,32)=1 -> conflict-free):
    //   in: [0..2]=pn, [3]=ts, [4]=tt; phase C: [0..6]=q,t; phase D: [0..2]=pts_out
    __shared__ uint32_t sBil[64 * 9];
    // sLf per point, stride 20 (16B-aligned): lf[16] -> lab[16] in place
    __shared__ float sLf[64 * 20];

    const int tid = threadIdx.x;
    const int base = blockIdx.x * 64;
    const int gid = base + tid;
    const bool valid = gid < KN;
    const int npts = min(64, KN - base);   // points in this block

    float px = 0.f, py = 0.f, pz = 0.f;
    float4 rq = make_float4(0.f, 0.f, 0.f, 0.f);

    // ---- Phase A0: per-thread input load (nontemporal), publish coords ----
    if (valid) {
        px = nt_loadf(&pts[gid * 3 + 0]);
        py = nt_loadf(&pts[gid * 3 + 1]);
        pz = nt_loadf(&pts[gid * 3 + 2]);
        rq = nt_load4(&reinterpret_cast<const float4*>(rots)[gid]);
        float ts = nt_loadf(&tsrc[gid]);
        float tt = nt_loadf(&ttgt[gid]);
        sBil[tid * 9 + 0] = __float_as_uint(-px);
        sBil[tid * 9 + 1] = __float_as_uint(-py);
        sBil[tid * 9 + 2] = __float_as_uint(-pz);
        sBil[tid * 9 + 3] = __float_as_uint(ts);
        sBil[tid * 9 + 4] = __float_as_uint(tt);
    }
    __syncthreads();

    const int g = tid >> 2, j = tid & 3;   // 16 groups of 4 lanes

    // ---- Phase A: cooperative Tl gather -> lf[16] in LDS (lane j owns labels 4j..4j+3) ----
    #pragma unroll
    for (int r = 0; r < 4; ++r) {
        int p = r * 16 + g;
        if (p < npts) {
            float pn0 = __uint_as_float(sBil[p * 9 + 0]);
            float pn1 = __uint_as_float(sBil[p * 9 + 1]);
            float pn2 = __uint_as_float(sBil[p * 9 + 2]);
            float a0 = 0.f, a1 = 0.f, a2 = 0.f, a3 = 0.f;
            #pragma unroll
            for (int pl = 0; pl < 3; ++pl) {
                float cx = (pl == 0) ? pn0 : (pl == 1) ? pn0 : pn1;
                float cy = (pl == 0) ? pn1 : (pl == 1) ? pn2 : pn2;
                float x = (cx + 1.0f) * 63.5f;
                float y = (cy + 1.0f) * 63.5f;
                float xf = floorf(x), yf = floorf(y);
                float wx = x - xf, wy = y - yf;
                int x0 = min((int)xf, KGRID - 1);
                int x1 = min(x0 + 1, KGRID - 1);
                int y0 = min((int)yf, KGRID - 1);
                int y1 = min(y0 + 1, KGRID - 1);
                const float4* B = Tl + (size_t)pl * (KGRID * KGRID * 4);
                float4 A = B[(y0 * KGRID + x0) * 4 + j];
                float4 Bc = B[(y0 * KGRID + x1) * 4 + j];
                float4 Cc = B[(y1 * KGRID + x0) * 4 + j];
                float4 D = B[(y1 * KGRID + x1) * 4 + j];
                float w00 = (1.f - wx) * (1.f - wy), w01 = wx * (1.f - wy);
                float w10 = (1.f - wx) * wy,          w11 = wx * wy;
                a0 = fmaf(w00, A.x, fmaf(w01, Bc.x, fmaf(w10, Cc.x, fmaf(w11, D.x, a0))));
                a1 = fmaf(w00, A.y, fmaf(w01, Bc.y, fmaf(w10, Cc.y, fmaf(w11, D.y, a1))));
                a2 = fmaf(w00, A.z, fmaf(w01, Bc.z, fmaf(w10, Cc.z, fmaf(w11, D.z, a2))));
                a3 = fmaf(w00, A.w, fmaf(w01, Bc.w, fmaf(w10, Cc.w, fmaf(w11, D.w, a3))));
            }
            *reinterpret_cast<float4*>(&sLf[p * 20 + j * 4]) = make_float4(a0, a1, a2, a3);
        }
    }
    __syncthreads();

    // ---- Phase B: per-thread softmax -> lab back into sLf ----
    if (valid) {
        float lf[16];
        #pragma unroll
        for (int m4 = 0; m4 < 4; ++m4) {
            float4 v = *reinterpret_cast<float4*>(&sLf[tid * 20 + m4 * 4]);
            lf[m4 * 4 + 0] = v.x; lf[m4 * 4 + 1] = v.y;
            lf[m4 * 4 + 2] = v.z; lf[m4 * 4 + 3] = v.w;
        }
        float mx = lf[0];
        #pragma unroll
        for (int k = 1; k < 16; ++k) mx = fmaxf(mx, lf[k]);
        float s = 0.f;
        float lab[16];
        #pragma unroll
        for (int k = 0; k < 16; ++k) {
            float e = __expf((lf[k] - mx) * 10.0f);
            lab[k] = e; s += e;
        }
        float rs = 1.0f / s;
        #pragma unroll
        for (int k = 0; k < 16; ++k) lab[k] *= rs;
        #pragma unroll
        for (int m4 = 0; m4 < 4; ++m4) {
            *reinterpret_cast<float4*>(&sLf[tid * 20 + m4 * 4]) =
                make_float4(lab[m4 * 4 + 0], lab[m4 * 4 + 1], lab[m4 * 4 + 2], lab[m4 * 4 + 3]);
        }
    }
    __syncthreads();

    // ---- Phase C: cooperative Tq/Tt gather + normalize + weighted sum -> qt in LDS ----
    #pragma unroll
    for (int r = 0; r < 4; ++r) {
        int p = r * 16 + g;
        if (p < npts) {
            float ts = __uint_as_float(sBil[p * 9 + 3]);
            float tt = __uint_as_float(sBil[p * 9 + 4]);
            float x = (ts + 1.0f) * 31.5f, y = (tt + 1.0f) * 31.5f;
            float xf = floorf(x), yf = floorf(y);
            float wx = x - xf, wy = y - yf;
            int x0 = min((int)xf, KTGRID - 1);
            int x1 = min(x0 + 1, KTGRID - 1);
            int y0 = min((int)yf, KTGRID - 1);
            int y1 = min(y0 + 1, KTGRID - 1);
            int c00 = y0 * KTGRID + x0, c01 = y0 * KTGRID + x1;
            int c10 = y1 * KTGRID + x0, c11 = y1 * KTGRID + x1;
            float w00 = (1.f - wx) * (1.f - wy), w01 = wx * (1.f - wy);
            float w10 = (1.f - wx) * wy,          w11 = wx * wy;

            // q part: lane j owns labels {j, 4+j, 8+j, 12+j} (f32)
            float q0 = 0.f, q1 = 0.f, q2 = 0.f, q3 = 0.f;
            #pragma unroll
            for (int m = 0; m < 4; ++m) {
                int l = m * 4 + j;
                float4 qa = Tq[c00 * 16 + l], qb = Tq[c01 * 16 + l];
                float4 qc4 = Tq[c10 * 16 + l], qd = Tq[c11 * 16 + l];
                float lw = sLf[p * 20 + l];
                float v0 = fmaf(w00, qa.x, fmaf(w01, qb.x, fmaf(w10, qc4.x, w11 * qd.x)));
                float v1 = fmaf(w00, qa.y, fmaf(w01, qb.y, fmaf(w10, qc4.y, w11 * qd.y)));
                float v2 = fmaf(w00, qa.z, fmaf(w01, qb.z, fmaf(w10, qc4.z, w11 * qd.z)));
                float v3 = fmaf(w00, qa.w, fmaf(w01, qb.w, fmaf(w10, qc4.w, w11 * qd.w)));
                float s2 = fmaxf(fmaf(v0, v0, fmaf(v1, v1, fmaf(v2, v2, v3 * v3))), 1e-24f);
                float rsq = rsqrtf(s2);
                rsq = rsq * fmaf(-0.5f * s2 * rsq, rsq, 1.5f);   // one NR step
                float wi = lw * rsq;
                q0 = fmaf(v0, wi, q0); q1 = fmaf(v1, wi, q1);
                q2 = fmaf(v2, wi, q2); q3 = fmaf(v3, wi, q3);
            }

            // t part: chunk n*4+j covers labels {8n+2j, 8n+2j+1} (bf16)
            float t0 = 0.f, t1 = 0.f, t2 = 0.f;
            #pragma unroll
            for (int n = 0; n < 2; ++n) {
                int ch = n * 4 + j;
                uint4 ua = Tt[c00 * 8 + ch], ub = Tt[c01 * 8 + ch];
                uint4 uc = Tt[c10 * 8 + ch], ud = Tt[c11 * 8 + ch];
                int lA = n * 8 + j * 2;
                float lwA = sLf[p * 20 + lA], lwB = sLf[p * 20 + lA + 1];
                float a0 = fmaf(w00, bf_lo(ua.x), fmaf(w01, bf_lo(ub.x), fmaf(w10, bf_lo(uc.x), w11 * bf_lo(ud.x))));
                float a1 = fmaf(w00, bf_hi(ua.x), fmaf(w01, bf_hi(ub.x), fmaf(w10, bf_hi(uc.x), w11 * bf_hi(ud.x))));
                float a2 = fmaf(w00, bf_lo(ua.y), fmaf(w01, bf_lo(ub.y), fmaf(w10, bf_lo(uc.y), w11 * bf_lo(ud.y))));
                float b0 = fmaf(w00, bf_lo(ua.z), fmaf(w01, bf_lo(ub.z), fmaf(w10, bf_lo(uc.z), w11 * bf_lo(ud.z))));
                float b1 = fmaf(w00, bf_hi(ua.z), fmaf(w01, bf_hi(ub.z), fmaf(w10, bf_hi(uc.z), w11 * bf_hi(ud.z))));
                float b2 = fmaf(w00, bf_lo(ua.w), fmaf(w01, bf_lo(ub.w), fmaf(w10, bf_lo(uc.w), w11 * bf_lo(ud.w))));
                t0 = fmaf(lwA, a0, fmaf(lwB, b0, t0));
                t1 = fmaf(lwA, a1, fmaf(lwB, b1, t1));
                t2 = fmaf(lwA, a2, fmaf(lwB, b2, t2));
            }

            q0 += __shfl_xor(q0, 1); q0 += __shfl_xor(q0, 2);
            q1 += __shfl_xor(q1, 1); q1 += __shfl_xor(q1, 2);
            q2 += __shfl_xor(q2, 1); q2 += __shfl_xor(q2, 2);
            q3 += __shfl_xor(q3, 1); q3 += __shfl_xor(q3, 2);
            t0 += __shfl_xor(t0, 1); t0 += __shfl_xor(t0, 2);
            t1 += __shfl_xor(t1, 1); t1 += __shfl_xor(t1, 2);
            t2 += __shfl_xor(t2, 1); t2 += __shfl_xor(t2, 2);
            if (j == 0) {
                sBil[p * 9 + 0] = __float_as_uint(q0);
                sBil[p * 9 + 1] = __float_as_uint(q1);
                sBil[p * 9 + 2] = __float_as_uint(q2);
                sBil[p * 9 + 3] = __float_as_uint(q3);
                sBil[p * 9 + 4] = __float_as_uint(t0);
                sBil[p * 9 + 5] = __float_as_uint(t1);
                sBil[p * 9 + 6] = __float_as_uint(t2);
            }
        }
    }
    __syncthreads();

    // ---- Phase D: per-thread quat math; rot stored directly (full-line);
    //      pts_out staged into sBil for cooperative full-line store ----
    if (valid) {
        float qw = __uint_as_float(sBil[tid * 9 + 0]);
        float qx = __uint_as_float(sBil[tid * 9 + 1]);
        float qy = __uint_as_float(sBil[tid * 9 + 2]);
        float qz = __uint_as_float(sBil[tid * 9 + 3]);
        float trx = __uint_as_float(sBil[tid * 9 + 4]);
        float tryy = __uint_as_float(sBil[tid * 9 + 5]);
        float trz = __uint_as_float(sBil[tid * 9 + 6]);

        float tw = -(qx * px + qy * py + qz * pz);
        float tx = qw * px + qy * pz - qz * py;
        float ty = qw * py - qx * pz + qz * px;
        float tz = qw * pz + qx * py - qy * px;
        float ox = -tw * qx + tx * qw - ty * qz + tz * qy;
        float oy = -tw * qy + tx * qz + ty * qw - tz * qx;
        float oz = -tw * qz - tx * qy + ty * qx + tz * qw;

        sBil[tid * 9 + 0] = __float_as_uint(ox + trx);
        sBil[tid * 9 + 1] = __float_as_uint(oy + tryy);
        sBil[tid * 9 + 2] = __float_as_uint(oz + trz);

        float rw = rq.x, rx = rq.y, ry = rq.z, rz = rq.w;
        float mw = qw * rw - qx * rx - qy * ry - qz * rz;
        float mx2 = qw * rx + qx * rw + qy * rz - qz * ry;
        float my = qw * ry - qx * rz + qy * rw + qz * rx;
        float mz = qw * rz + qx * ry - qy * rx + qz * rw;
        if (mw < 0.0f) { mw = -mw; mx2 = -mx2; my = -my; mz = -mz; }
        nt_store4(&reinterpret_cast<float4*>(out + (size_t)KN * 3)[gid],
                  make_float4(mw, mx2, my, mz));
    }
    __syncthreads();

    // ---- Phase E: cooperative full-line stores (consecutive lanes -> consecutive 16B) ----
    {
        // pts_out: npts*3 floats starting at out + base*3
        int nf4 = (npts * 3) >> 2;            // full float4s (48 for full block)
        if (tid < nf4) {
            int i = tid * 4;
            float4 v = make_float4(
                __uint_as_float(sBil[(i / 3) * 9 + (i % 3)]),
                __uint_as_float(sBil[((i + 1) / 3) * 9 + ((i + 1) % 3)]),
                __uint_as_float(sBil[((i + 2) / 3) * 9 + ((i + 2) % 3)]),
                __uint_as_float(sBil[((i + 3) / 3) * 9 + ((i + 3) % 3)]));
            nt_store4(&out[(size_t)base * 3 + i], v);
        }
        int rem = npts * 3 - nf4 * 4;          // 0 for full blocks
        if (tid < rem) {
            int i = nf4 * 4 + tid;
            nt_storef(&out[(size_t)base * 3 + i],
                      __uint_as_float(sBil[(i / 3) * 9 + (i % 3)]));
        }
        // labels: npts*16 floats starting at out + KN*7 + base*16
        float* lb = out + (size_t)KN * 7 + (size_t)base * 16;
        #pragma unroll
        for (int it = 0; it < 4; ++it) {
            int i = it * 64 + tid;             // float4 index
            if (i < npts * 4) {
                int p = i >> 2, e = i & 3;
                float4 v = *reinterpret_cast<float4*>(&sLf[p * 20 + e * 4]);
                nt_store4(&lb[i * 4], v);
            }
        }
    }
}

// ======== fallback (round-1 kernel, used only if ws_size too small) ========
struct Bilin { int i00, i01, i10, i11; float w00, w01, w10, w11; };

__device__ __forceinline__ Bilin make_bilin(float cx, float cy, int W, int H) {
    float x = (cx + 1.0f) * 0.5f * (float)(W - 1);
    float y = (cy + 1.0f) * 0.5f * (float)(H - 1);
    float x0f = floorf(x), y0f = floorf(y);
    float wx = x - x0f, wy = y - y0f;
    int x0 = max(0, min((int)x0f, W - 1));
    int x1 = min(x0 + 1, W - 1);
    int y0 = max(0, min((int)y0f, H - 1));
    int y1 = min(y0 + 1, H - 1);
    Bilin b;
    b.i00 = y0 * W + x0; b.i01 = y0 * W + x1;
    b.i10 = y1 * W + x0; b.i11 = y1 * W + x1;
    b.w00 = (1.0f - wx) * (1.0f - wy); b.w01 = wx * (1.0f - wy);
    b.w10 = (1.0f - wx) * wy;          b.w11 = wx * wy;
    return b;
}

__global__ __launch_bounds__(256) void hexplane_fallback(
    const float* __restrict__ pts, const float* __restrict__ rots,
    const float* __restrict__ tsrc, const float* __restrict__ ttgt,
    const float* __restrict__ label_planes, const float* __restrict__ deform_plane,
    const float* __restrict__ W_label, const float* __restrict__ W_deform,
    float* __restrict__ out)
{
    __shared__ float sWd[112 * KC];
    __shared__ float sWl[KL * 72];
    for (int i = threadIdx.x; i < 112 * KC; i += blockDim.x) sWd[i] = W_deform[i];
    for (int i = threadIdx.x; i < KL * 72; i += blockDim.x) sWl[i] = W_label[i];
    __syncthreads();
    int idx = blockIdx.x * blockDim.x + threadIdx.x;
    if (idx >= KN) return;
    float px = pts[idx*3], py = pts[idx*3+1], pz = pts[idx*3+2];
    float4 rq = reinterpret_cast<const float4*>(rots)[idx];
    Bilin bd = make_bilin(tsrc[idx], ttgt[idx], KTGRID, KTGRID);
    float tfeat[KC];
    #pragma unroll
    for (int c = 0; c < KC; ++c) {
        const float* pl = deform_plane + c * (KTGRID * KTGRID);
        tfeat[c] = fmaf(bd.w11, pl[bd.i11], fmaf(bd.w10, pl[bd.i10], fmaf(bd.w01, pl[bd.i01], bd.w00 * pl[bd.i00])));
    }
    float pn0 = -px, pn1 = -py, pn2 = -pz;
    float lf[KL];
    #pragma unroll
    for (int k = 0; k < KL; ++k) lf[k] = 0.0f;
    #pragma unroll
    for (int p = 0; p < 3; ++p) {
        float cx = (p == 0) ? pn0 : (p == 1) ? pn0 : pn1;
        float cy = (p == 0) ? pn1 : (p == 1) ? pn2 : pn2;
        Bilin bl = make_bilin(cx, cy, KGRID, KGRID);
        const float* plane_p = label_planes + p * (KC * KGRID * KGRID);
        #pragma unroll
        for (int c = 0; c < KC; ++c) {
            const float* pl = plane_p + c * (KGRID * KGRID);
            float v = fmaf(bl.w11, pl[bl.i11], fmaf(bl.w10, pl[bl.i10], fmaf(bl.w01, pl[bl.i01], bl.w00 * pl[bl.i00])));
            #pragma unroll
            for (int k = 0; k < KL; ++k) lf[k] = fmaf(v, sWl[k * 72 + p * KC + c], lf[k]);
        }
    }
    float m = lf[0];
    #pragma unroll
    for (int k = 1; k < KL; ++k) m = fmaxf(m, lf[k]);
    float lab[KL], ssum = 0.0f;
    #pragma unroll
    for (int k = 0; k < KL; ++k) { float e = __expf((lf[k] - m) * 10.0f); lab[k] = e; ssum += e; }
    float rs = 1.0f / ssum;
    #pragma unroll
    for (int k = 0; k < KL; ++k) lab[k] *= rs;
    float qw = 0, qx = 0, qy = 0, qz = 0, trx = 0, tryy = 0, trz = 0;
    #pragma unroll
    for (int l = 0; l < KL; ++l) {
        float d[7];
        #pragma unroll
        for (int jj = 0; jj < 7; ++jj) {
            const float* wr = sWd + (l * 7 + jj) * KC;
            float acc = 0.0f;
            #pragma unroll
            for (int c = 0; c < KC; ++c) acc = fmaf(tfeat[c], wr[c], acc);
            d[jj] = acc;
        }
        float inv = 1.0f / fmaxf(sqrtf(d[0]*d[0]+d[1]*d[1]+d[2]*d[2]+d[3]*d[3]), 1e-12f);
        float w = lab[l], wi = w * inv;
        qw = fmaf(d[0], wi, qw); qx = fmaf(d[1], wi, qx); qy = fmaf(d[2], wi, qy); qz = fmaf(d[3], wi, qz);
        trx = fmaf(d[4], w, trx); tryy = fmaf(d[5], w, tryy); trz = fmaf(d[6], w, trz);
    }
    float tw = -(qx*px + qy*py + qz*pz);
    float tx = qw*px + qy*pz - qz*py;
    float ty = qw*py - qx*pz + qz*px;
    float tz = qw*pz + qx*py - qy*px;
    out[idx*3+0] = -tw*qx + tx*qw - ty*qz + tz*qy + trx;
    out[idx*3+1] = -tw*qy + tx*qz + ty*qw - tz*qx + tryy;
    out[idx*3+2] = -tw*qz - tx*qy + ty*qx + tz*qw + trz;
    float rw = rq.x, rx = rq.y, ry = rq.z, rz = rq.w;
    float mw = qw*rw - qx*rx - qy*ry - qz*rz;
    float mx = qw*rx + qx*rw + qy*rz - qz*ry;
    float my = qw*ry - qx*rz + qy*rw + qz*rx;
    float mz = qw*rz + qx*ry - qy*rx + qz*rw;
    if (mw < 0.0f) { mw = -mw; mx = -mx; my = -my; mz = -mz; }
    reinterpret_cast<float4*>(out + (size_t)KN * 3)[idx] = make_float4(mw, mx, my, mz);
    float4* lab_out = reinterpret_cast<float4*>(out + (size_t)KN * 7);
    #pragma unroll
    for (int k = 0; k < 4; ++k)
        lab_out[idx*4+k] = make_float4(lab[k*4], lab[k*4+1], lab[k*4+2], lab[k*4+3]);
}

extern "C" void kernel_launch(void* const* d_in, const int* in_sizes, int n_in,
                              void* d_out, int out_size, void* d_ws, size_t ws_size,
                              hipStream_t stream) {
    const float* pts  = (const float*)d_in[0];
    const float* rots = (const float*)d_in[1];
    const float* ts   = (const float*)d_in[2];
    const float* tt   = (const float*)d_in[3];
    const float* lp   = (const float*)d_in[4];
    const float* dp   = (const float*)d_in[5];
    const float* wl   = (const float*)d_in[6];
    const float* wd   = (const float*)d_in[7];
    float* out = (float*)d_out;

    if (ws_size < WS_NEEDED) {
        hexplane_fallback<<<dim3((KN + 255) / 256), dim3(256), 0, stream>>>(
            pts, rots, ts, tt, lp, dp, wl, wd, out);
        return;
    }

    unsigned char* ws = (unsigned char*)d_ws;
    float4* Tq = (float4*)ws;
    uint2*  Tt = (uint2*)(ws + TQ_BYTES);
    float4* Tl = (float4*)(ws + TQ_BYTES + TT_BYTES);

    xform_all<<<dim3(448), dim3(256), 0, stream>>>(dp, wd, lp, wl, Tq, Tt, Tl);
    hexplane_main<<<dim3((KN + 63) / 64), dim3(64), 0, stream>>>(
        pts, rots, ts, tt, Tq, (const uint4*)Tt, Tl, out);
}